// Round 11
// baseline (182.055 us; speedup 1.0000x reference)
//
#include <hip/hip_runtime.h>
#include <hip/hip_bf16.h>

// SelfAttention (channel attention) on MI355X. Inputs fp32, OUTPUT fp32.
//   Hn = GN(x) (bf16, row-major + transposed HnT)
//   G_b = Hn_b^T Hn_b ; L_b = Wq^T G_b Wk + rank-1 bias terms
//   attn_b = softmax_rows(L_b) ; attnbv[k] = attn_b[k,:]·bv
//   CT_b = (Wp^T attn_b) Wv^T ; dv = Wp^T attnbv
//   out = x + Hn CT_b^T + dv + bp
// R11: k_final's dv gemv was a 64-deep serial load chain gating the first
//      barrier (~7us/block; cause of the R7+ 50-60us plateau vs R6's 38).
//      -> parallel 256-thread dv partials, fully unrolled. Also: gram
//      partials bf16 (halves part traffic).

using bf16   = __bf16;
using bf16x8 = __attribute__((ext_vector_type(8))) __bf16;
using bf16x4 = __attribute__((ext_vector_type(4))) __bf16;
using f32x4  = __attribute__((ext_vector_type(4))) float;

#define DI __device__ __forceinline__

DI void gload16(const bf16* g, bf16* l) {
  __builtin_amdgcn_global_load_lds(
      (const __attribute__((address_space(1))) void*)g,
      (__attribute__((address_space(3))) void*)l, 16, 0, 0);
}

// ---------------- 128x128 tile core: gload_lds staging + XOR-swizzled reads ----
DI void gemm128_core(const bf16* __restrict__ A, long lda,
                     const bf16* __restrict__ B, long ldb,
                     int ksteps, bf16* As, bf16* Bs, f32x4 acc[4][4]) {
  const int tid  = threadIdx.x;
  const int lane = tid & 63;
  const int w    = tid >> 6;
  const int lr   = lane & 15;
  const int lk   = (lane >> 4) * 8;
  const int wr   = (w >> 1) * 64;
  const int wc   = (w & 1) * 64;
  const int sw   = (lr & 7) << 3;

  const int  srow = lane >> 3;                       // 0..7
  const int  ssw  = ((lane & 7) ^ srow) << 3;        // pre-swizzled col
  const bf16* ga = A + (long)(w * 8 + srow) * lda + ssw;
  const bf16* gb = B + (long)(w * 8 + srow) * ldb + ssw;
  bf16* lA = As + w * 512;                           // wave-uniform LDS base
  bf16* lB = Bs + w * 512;

  for (int kt = 0; kt < ksteps; ++kt) {
#pragma unroll
    for (int c = 0; c < 4; ++c) {
      gload16(ga + (long)c * 32 * lda, lA + c * 2048);
      gload16(gb + (long)c * 32 * ldb, lB + c * 2048);
    }
    ga += 64; gb += 64;
    __syncthreads();
#pragma unroll
    for (int kk = 0; kk < 2; ++kk) {
      bf16x8 af[4], bfr[4];
#pragma unroll
      for (int i = 0; i < 4; ++i)
        af[i] = *(const bf16x8*)(As + (wr + i * 16 + lr) * 64 + ((kk * 32 + lk) ^ sw));
#pragma unroll
      for (int i = 0; i < 4; ++i)
        bfr[i] = *(const bf16x8*)(Bs + (wc + i * 16 + lr) * 64 + ((kk * 32 + lk) ^ sw));
#pragma unroll
      for (int i = 0; i < 4; ++i)
#pragma unroll
        for (int j = 0; j < 4; ++j)
          acc[i][j] = __builtin_amdgcn_mfma_f32_16x16x32_bf16(af[i], bfr[j], acc[i][j], 0, 0, 0);
    }
    __syncthreads();
  }
}

// ---------------- 128x64 tile core (k_final) ----------
DI void gemm128x64_core(const bf16* __restrict__ A, long lda,
                        const bf16* __restrict__ B, long ldb,
                        int ksteps, bf16* As, bf16* Bs, f32x4 acc[4][2]) {
  const int tid  = threadIdx.x;
  const int lane = tid & 63;
  const int w    = tid >> 6;
  const int lr   = lane & 15;
  const int lk   = (lane >> 4) * 8;
  const int wr   = (w >> 1) * 64;      // M-half
  const int wc   = (w & 1) * 32;       // N-half
  const int sw   = (lr & 7) << 3;

  const int  srow = lane >> 3;
  const int  ssw  = ((lane & 7) ^ srow) << 3;
  const bf16* ga = A + (long)(w * 8 + srow) * lda + ssw;
  const bf16* gb = B + (long)(w * 8 + srow) * ldb + ssw;
  bf16* lA = As + w * 512;
  bf16* lB = Bs + w * 512;

  for (int kt = 0; kt < ksteps; ++kt) {
#pragma unroll
    for (int c = 0; c < 4; ++c)
      gload16(ga + (long)c * 32 * lda, lA + c * 2048);
#pragma unroll
    for (int c = 0; c < 2; ++c)
      gload16(gb + (long)c * 32 * ldb, lB + c * 2048);
    ga += 64; gb += 64;
    __syncthreads();
#pragma unroll
    for (int kk = 0; kk < 2; ++kk) {
      bf16x8 af[4], bfr[2];
#pragma unroll
      for (int i = 0; i < 4; ++i)
        af[i] = *(const bf16x8*)(As + (wr + i * 16 + lr) * 64 + ((kk * 32 + lk) ^ sw));
#pragma unroll
      for (int j = 0; j < 2; ++j)
        bfr[j] = *(const bf16x8*)(Bs + (wc + j * 16 + lr) * 64 + ((kk * 32 + lk) ^ sw));
#pragma unroll
      for (int i = 0; i < 4; ++i)
#pragma unroll
        for (int j = 0; j < 2; ++j)
          acc[i][j] = __builtin_amdgcn_mfma_f32_16x16x32_bf16(af[i], bfr[j], acc[i][j], 0, 0, 0);
    }
    __syncthreads();
  }
}

// ---------------- 64x64 tile core ----------------
DI void gemm64_core(const bf16* __restrict__ A, long lda,
                    const bf16* __restrict__ B, long ldb,
                    int ksteps, bf16* As, bf16* Bs, f32x4 acc[2][2]) {
  const int tid  = threadIdx.x;
  const int lane = tid & 63;
  const int w    = tid >> 6;
  const int lr   = lane & 15;
  const int lk   = (lane >> 4) * 8;
  const int wr   = (w >> 1) * 32;
  const int wc   = (w & 1) * 32;
  const int sw   = (lr & 7) << 3;

  const int  srow = lane >> 3;
  const int  ssw  = ((lane & 7) ^ srow) << 3;
  const bf16* ga = A + (long)(w * 8 + srow) * lda + ssw;
  const bf16* gb = B + (long)(w * 8 + srow) * ldb + ssw;
  bf16* lA = As + w * 512;
  bf16* lB = Bs + w * 512;

  for (int kt = 0; kt < ksteps; ++kt) {
#pragma unroll
    for (int c = 0; c < 2; ++c) {
      gload16(ga + (long)c * 32 * lda, lA + c * 2048);
      gload16(gb + (long)c * 32 * ldb, lB + c * 2048);
    }
    ga += 64; gb += 64;
    __syncthreads();
#pragma unroll
    for (int kk = 0; kk < 2; ++kk) {
      bf16x8 af[2], bfr[2];
#pragma unroll
      for (int i = 0; i < 2; ++i)
        af[i] = *(const bf16x8*)(As + (wr + i * 16 + lr) * 64 + ((kk * 32 + lk) ^ sw));
#pragma unroll
      for (int i = 0; i < 2; ++i)
        bfr[i] = *(const bf16x8*)(Bs + (wc + i * 16 + lr) * 64 + ((kk * 32 + lk) ^ sw));
#pragma unroll
      for (int i = 0; i < 2; ++i)
#pragma unroll
        for (int j = 0; j < 2; ++j)
          acc[i][j] = __builtin_amdgcn_mfma_f32_16x16x32_bf16(af[i], bfr[j], acc[i][j], 0, 0, 0);
    }
    __syncthreads();
  }
}

// ---------------- prep: GN stats (blocks 0..255) + weight transpose (256..1279) ----------------
__global__ __launch_bounds__(256) void k_prep(const float* __restrict__ x,
                                              const float* __restrict__ wq,
                                              const float* __restrict__ wk,
                                              const float* __restrict__ wv,
                                              const float* __restrict__ wp,
                                              bf16* __restrict__ WT,
                                              bf16* __restrict__ wvb,
                                              float* __restrict__ s,
                                              float2* __restrict__ stats) {
  __shared__ float shm[1056];
  const int tid = threadIdx.x;
  const int bx = blockIdx.x;
  if (bx < 256) {
    const int b = bx >> 5, g = bx & 31;
    const float* base = x + (size_t)b * 4096 * 512 + g * 16;
    float sm = 0.f, ss = 0.f;
    for (int it = 0; it < 64; ++it) {
      const int idx = it * 256 + tid;
      const int p = idx >> 2, c4 = (idx & 3) * 4;
      float4 v = *(const float4*)(base + (size_t)p * 512 + c4);
      sm += v.x + v.y + v.z + v.w;
      ss += v.x * v.x + v.y * v.y + v.z * v.z + v.w * v.w;
    }
    float* rs = shm; float* rss = shm + 256;
    rs[tid] = sm; rss[tid] = ss; __syncthreads();
    for (int off = 128; off; off >>= 1) {
      if (tid < off) { rs[tid] += rs[tid + off]; rss[tid] += rss[tid + off]; }
      __syncthreads();
    }
    if (tid == 0) {
      float mean = rs[0] * (1.f / 65536.f);
      float var  = rss[0] * (1.f / 65536.f) - mean * mean;
      stats[bx] = float2{mean, rsqrtf(var + 1e-5f)};
    }
  } else {
    const int r = bx - 256;             // 0..1023
    const int z = r >> 8;
    const int r2 = r & 255;
    const int bxx = r2 & 15, byy = r2 >> 4;
    const int tx = tid & 31, ty = tid >> 5;
    const float* src = (z == 0) ? wq : (z == 1) ? wk : (z == 2) ? wv : wp;
    const int n0 = bxx * 32, k0 = byy * 32;
    if (z == 0 && byy == 0) s[bxx * 256 + tid] = 0.f;
#pragma unroll
    for (int j = 0; j < 4; ++j) {
      const float v = src[(size_t)(k0 + ty + j * 8) * 512 + n0 + tx];
      shm[(ty + j * 8) * 33 + tx] = v;
      if (z == 2) wvb[(size_t)(k0 + ty + j * 8) * 512 + n0 + tx] = (bf16)v;
    }
    __syncthreads();
#pragma unroll
    for (int j = 0; j < 4; ++j)
      WT[(size_t)(z * 512 + n0 + ty + j * 8) * 512 + k0 + tx] = (bf16)shm[tx * 33 + ty + j * 8];
  }
}

// ---------------- GN apply -> Hn + HnT + col-sums s ----------------
__global__ __launch_bounds__(256) void k_gnapply_t(const float* __restrict__ x,
                                                   const float2* __restrict__ stats,
                                                   const float* __restrict__ gns,
                                                   const float* __restrict__ gnb,
                                                   bf16* __restrict__ Hn,
                                                   bf16* __restrict__ HnT,
                                                   float* __restrict__ s) {
  __shared__ bf16 tile[64 * 516];
  __shared__ float cs[512];
  const int tid = threadIdx.x;
  const int blk = blockIdx.x;       // 0..511
  const int b = blk >> 6, p0 = (blk & 63) * 64;
  cs[tid] = 0.f; cs[tid + 256] = 0.f;
  __syncthreads();

  const int c4 = (tid & 127) * 4;
  const int hi = tid >> 7;
  const float2 st = stats[b * 32 + (c4 >> 4)];
  const float4 sc = *(const float4*)(gns + c4);
  const float4 bi = *(const float4*)(gnb + c4);
  float a0 = 0.f, a1 = 0.f, a2 = 0.f, a3 = 0.f;
  for (int i = 0; i < 32; ++i) {
    const int px = i * 2 + hi;
    const float4 xv = *(const float4*)(x + ((size_t)(b * 4096 + p0 + px)) * 512 + c4);
    const float h0 = (xv.x - st.x) * st.y * sc.x + bi.x;
    const float h1 = (xv.y - st.x) * st.y * sc.y + bi.y;
    const float h2 = (xv.z - st.x) * st.y * sc.z + bi.z;
    const float h3 = (xv.w - st.x) * st.y * sc.w + bi.w;
    a0 += h0; a1 += h1; a2 += h2; a3 += h3;
    bf16x4 hv;
    hv[0] = (bf16)h0; hv[1] = (bf16)h1; hv[2] = (bf16)h2; hv[3] = (bf16)h3;
    *(bf16x4*)(Hn + ((size_t)(b * 4096 + p0 + px)) * 512 + c4) = hv;
    *(bf16x4*)(tile + px * 516 + c4) = hv;
  }
  atomicAdd(&cs[c4 + 0], a0); atomicAdd(&cs[c4 + 1], a1);
  atomicAdd(&cs[c4 + 2], a2); atomicAdd(&cs[c4 + 3], a3);
  __syncthreads();
  atomicAdd(s + b * 512 + tid, cs[tid]);
  atomicAdd(s + b * 512 + 256 + tid, cs[tid + 256]);

  for (int cg = 0; cg < 16; ++cg) {
    const int c  = cg * 32 + (tid >> 3);
    const int so = (tid & 7) * 8;
    bf16x8 pk;
#pragma unroll
    for (int k = 0; k < 8; ++k) pk[k] = tile[(so + k) * 516 + c];
    *(bf16x8*)(HnT + ((size_t)(b * 512 + c)) * 4096 + p0 + so) = pk;
  }
}

// ---------------- Gram: symmetric tiles, split-K=4, xcd==batch; bf16 partials ----------------
__global__ __launch_bounds__(256) void k_gram(const bf16* __restrict__ HnT,
                                              bf16* __restrict__ part) {
  __shared__ bf16 As[128 * 64], Bs[128 * 64];
  const int Lb = blockIdx.x;           // 0..319 ; xcd = Lb%8 = batch
  const int b  = Lb & 7;
  const int idx = Lb >> 3;             // 0..39
  const int sp = idx & 3;
  const int t  = idx >> 2;             // 0..9 upper-tri tile id
  const int m0 = (int)((0x3221110000ull >> (4 * t)) & 15) * 128;
  const int n0 = (int)((0x3323213210ull >> (4 * t)) & 15) * 128;
  f32x4 acc[4][4];
#pragma unroll
  for (int i = 0; i < 4; ++i)
#pragma unroll
    for (int j = 0; j < 4; ++j) acc[i][j] = (f32x4){0.f, 0.f, 0.f, 0.f};
  const bf16* A = HnT + ((size_t)b * 512 + m0) * 4096 + sp * 1024;
  const bf16* B = HnT + ((size_t)b * 512 + n0) * 4096 + sp * 1024;
  gemm128_core(A, 4096, B, 4096, 16, As, Bs, acc);

  const int lane = threadIdx.x & 63, w = threadIdx.x >> 6;
  const int wr = (w >> 1) * 64, wc = (w & 1) * 64;
  const int rr = (lane >> 4) * 4, cc = lane & 15;
  bf16* dst = part + (size_t)(sp * 8 + b) * 262144;
#pragma unroll
  for (int i = 0; i < 4; ++i) {
#pragma unroll
    for (int j = 0; j < 4; ++j) {
      const int gm = m0 + wr + i * 16 + rr;
      const int gn = n0 + wc + j * 16 + cc;
      bf16* p = dst + (size_t)gm * 512 + gn;
      p[0]    = (bf16)acc[i][j][0];
      p[512]  = (bf16)acc[i][j][1];
      p[1024] = (bf16)acc[i][j][2];
      p[1536] = (bf16)acc[i][j][3];
      if (m0 != n0) {                  // mirror (G symmetric)
        bf16x4 pk;
        pk[0] = (bf16)acc[i][j][0]; pk[1] = (bf16)acc[i][j][1];
        pk[2] = (bf16)acc[i][j][2]; pk[3] = (bf16)acc[i][j][3];
        *(bf16x4*)(dst + (size_t)gn * 512 + gm) = pk;
      }
    }
  }
}

// ---------------- gsum (blocks 0..2047) + uq/vkv small gemv (2048..2063) ----------------
__global__ __launch_bounds__(256) void k_gsumv(const bf16* __restrict__ part,
                                               bf16* __restrict__ G,
                                               const bf16* __restrict__ WT,
                                               const float* __restrict__ s,
                                               float* __restrict__ uq,
                                               float* __restrict__ vkv) {
  const int bx = blockIdx.x, tid = threadIdx.x;
  if (bx < 2048) {
    const size_t S8 = (size_t)8 * 262144;
    const size_t i4 = ((size_t)bx * 256 + tid) * 4;
    const bf16x4 a = *(const bf16x4*)(part + i4);
    const bf16x4 c = *(const bf16x4*)(part + i4 + S8);
    const bf16x4 d = *(const bf16x4*)(part + i4 + 2 * S8);
    const bf16x4 e = *(const bf16x4*)(part + i4 + 3 * S8);
    bf16x4 o;
#pragma unroll
    for (int j = 0; j < 4; ++j)
      o[j] = (bf16)((float)a[j] + (float)c[j] + (float)d[j] + (float)e[j]);
    *(bf16x4*)(G + i4) = o;
  } else {
    const int z = bx - 2048;            // 0..15
    const int which = z >> 3, b = z & 7;
    const float* sv = s + b * 512;
    for (int o = tid; o < 512; o += 256) {
      const bf16* row = WT + ((size_t)(which * 512 + o)) * 512;
      float acc = 0.f;
      for (int c = 0; c < 512; c += 8) {
        bf16x8 v = *(const bf16x8*)(row + c);
        const float4 s0 = *(const float4*)(sv + c);
        const float4 s1 = *(const float4*)(sv + c + 4);
        acc += (float)v[0] * s0.x + (float)v[1] * s0.y + (float)v[2] * s0.z +
               (float)v[3] * s0.w + (float)v[4] * s1.x + (float)v[5] * s1.y +
               (float)v[6] * s1.z + (float)v[7] * s1.w;
      }
      (which == 0 ? uq : vkv)[b * 512 + o] = acc;
    }
  }
}

// ---------------- batched small GEMM 512x512x512, bf16 out ----------------
__global__ __launch_bounds__(256) void k_sg64_bf(const bf16* __restrict__ Ab, long a_bs,
                                                 const bf16* __restrict__ Bb, long b_bs,
                                                 bf16* __restrict__ Cb) {
  __shared__ bf16 As[64 * 64], Bs[64 * 64];
  const int b = blockIdx.z;
  const int m0 = blockIdx.y * 64, n0 = blockIdx.x * 64;
  f32x4 acc[2][2];
#pragma unroll
  for (int i = 0; i < 2; ++i)
#pragma unroll
    for (int j = 0; j < 2; ++j) acc[i][j] = (f32x4){0.f, 0.f, 0.f, 0.f};
  gemm64_core(Ab + (size_t)b * a_bs + (size_t)m0 * 512, 512,
              Bb + (size_t)b * b_bs + (size_t)n0 * 512, 512, 8, As, Bs, acc);

  const int lane = threadIdx.x & 63, w = threadIdx.x >> 6;
  const int wr = (w >> 1) * 32, wc = (w & 1) * 32;
  const int rr = (lane >> 4) * 4, cc = lane & 15;
  bf16* dst = Cb + (size_t)b * 262144;
#pragma unroll
  for (int i = 0; i < 2; ++i) {
#pragma unroll
    for (int j = 0; j < 2; ++j) {
      const int gm = m0 + wr + i * 16 + rr;
      const int gn = n0 + wc + j * 16 + cc;
      bf16* p = dst + (size_t)gm * 512 + gn;
      p[0]    = (bf16)acc[i][j][0];
      p[512]  = (bf16)acc[i][j][1];
      p[1024] = (bf16)acc[i][j][2];
      p[1536] = (bf16)acc[i][j][3];
    }
  }
}

// ---------------- batched small GEMM 512x512x512, fp32 out ----------------
__global__ __launch_bounds__(256) void k_sg64_f32(const bf16* __restrict__ Ab, long a_bs,
                                                  const bf16* __restrict__ Bb, long b_bs,
                                                  float* __restrict__ Cb) {
  __shared__ bf16 As[64 * 64], Bs[64 * 64];
  const int b = blockIdx.z;
  const int m0 = blockIdx.y * 64, n0 = blockIdx.x * 64;
  f32x4 acc[2][2];
#pragma unroll
  for (int i = 0; i < 2; ++i)
#pragma unroll
    for (int j = 0; j < 2; ++j) acc[i][j] = (f32x4){0.f, 0.f, 0.f, 0.f};
  gemm64_core(Ab + (size_t)b * a_bs + (size_t)m0 * 512, 512,
              Bb + (size_t)b * b_bs + (size_t)n0 * 512, 512, 8, As, Bs, acc);

  const int lane = threadIdx.x & 63, w = threadIdx.x >> 6;
  const int wr = (w >> 1) * 32, wc = (w & 1) * 32;
  const int rr = (lane >> 4) * 4, cc = lane & 15;
  float* dst = Cb + (size_t)b * 262144;
#pragma unroll
  for (int i = 0; i < 2; ++i) {
#pragma unroll
    for (int j = 0; j < 2; ++j) {
      const int gm = m0 + wr + i * 16 + rr;
      const int gn = n0 + wc + j * 16 + cc;
      float* p = dst + (size_t)gm * 512 + gn;
      p[0]    = acc[i][j][0];
      p[512]  = acc[i][j][1];
      p[1024] = acc[i][j][2];
      p[1536] = acc[i][j][3];
    }
  }
}

// ---------------- softmax (4 rows/block, wave-shuffle) -> attnT + attnbv ----------------
__global__ __launch_bounds__(256) void k_smax(const float* __restrict__ L,
                                              const float* __restrict__ uq,
                                              const float* __restrict__ vkv,
                                              const float* __restrict__ bq,
                                              const float* __restrict__ bk,
                                              const float* __restrict__ bv,
                                              bf16* __restrict__ attnT,
                                              float* __restrict__ attnbv) {
  __shared__ bf16 p[4][512];
  const int tid = threadIdx.x;
  const int w = tid >> 6, l = tid & 63;
  const int blk = blockIdx.x;          // 0..1023, 4 rows each
  const int gr = blk * 4 + w;          // global row
  const int b = gr >> 9, i = gr & 511;
  const int c = l * 8;

  const float r  = uq[b * 512 + i];
  const float q0 = bq[i];
  const float* lp = L + (size_t)gr * 512 + c;
  const float4 l0 = *(const float4*)lp;
  const float4 l1 = *(const float4*)(lp + 4);
  const float4 k0 = *(const float4*)(bk + c);
  const float4 k1 = *(const float4*)(bk + c + 4);
  const float4 g0 = *(const float4*)(vkv + b * 512 + c);
  const float4 g1 = *(const float4*)(vkv + b * 512 + c + 4);
  float v[8];
  v[0] = l0.x + r * k0.x + q0 * (g0.x + 4096.f * k0.x);
  v[1] = l0.y + r * k0.y + q0 * (g0.y + 4096.f * k0.y);
  v[2] = l0.z + r * k0.z + q0 * (g0.z + 4096.f * k0.z);
  v[3] = l0.w + r * k0.w + q0 * (g0.w + 4096.f * k0.w);
  v[4] = l1.x + r * k1.x + q0 * (g1.x + 4096.f * k1.x);
  v[5] = l1.y + r * k1.y + q0 * (g1.y + 4096.f * k1.y);
  v[6] = l1.z + r * k1.z + q0 * (g1.z + 4096.f * k1.z);
  v[7] = l1.w + r * k1.w + q0 * (g1.w + 4096.f * k1.w);

  float mx = v[0];
#pragma unroll
  for (int j = 1; j < 8; ++j) mx = fmaxf(mx, v[j]);
  for (int off = 32; off; off >>= 1) mx = fmaxf(mx, __shfl_xor(mx, off));
  float e[8], sm = 0.f;
#pragma unroll
  for (int j = 0; j < 8; ++j) { e[j] = __expf(v[j] - mx); sm += e[j]; }
  for (int off = 32; off; off >>= 1) sm += __shfl_xor(sm, off);
  const float inv = 1.f / sm;

  const float4 b0 = *(const float4*)(bv + c);
  const float4 b1 = *(const float4*)(bv + c + 4);
  float ab = e[0] * b0.x + e[1] * b0.y + e[2] * b0.z + e[3] * b0.w +
             e[4] * b1.x + e[5] * b1.y + e[6] * b1.z + e[7] * b1.w;
  ab *= inv;
  for (int off = 32; off; off >>= 1) ab += __shfl_xor(ab, off);
  if (l == 0) attnbv[gr] = ab;

  bf16x8 o;
#pragma unroll
  for (int j = 0; j < 8; ++j) o[j] = (bf16)(e[j] * inv);
  *(bf16x8*)(&p[w][c]) = o;
  __syncthreads();

  const int i0 = (blk * 4) & 511;
  for (int n = tid; n < 512; n += 256) {
    bf16x4 t;
    t[0] = p[0][n]; t[1] = p[1][n]; t[2] = p[2][n]; t[3] = p[3][n];
    *(bf16x4*)(attnT + (size_t)b * 262144 + (size_t)n * 512 + i0) = t;
  }
}

// ---------------- final: out = x + Hn CT^T + dv + bp ; 128x64 tiles, xcd==batch ----------------
__global__ __launch_bounds__(256) void k_final(const bf16* __restrict__ Hn,
                                               const bf16* __restrict__ CT,
                                               const float* __restrict__ attnbv,
                                               const bf16* __restrict__ WTp,
                                               const float* __restrict__ bp,
                                               const float* __restrict__ x,
                                               float* __restrict__ out) {
  __shared__ bf16 As[128 * 64], Bs[64 * 64];
  __shared__ float abvs[512], dvp[64][4];
  const int Lb = blockIdx.x;           // 0..2047 ; xcd = Lb%8 = batch
  const int b  = Lb & 7;
  const int idx = Lb >> 3;             // 0..255
  const int m0 = (idx >> 3) * 128;     // 32 M-tiles
  const int n0 = (idx & 7) * 64;       // 8 N-tiles
  const int tid = threadIdx.x;

  for (int cch = tid; cch < 512; cch += 256)
    abvs[cch] = attnbv[b * 512 + cch];
  __syncthreads();
  // dv partials: thread (o = tid&63, q = tid>>6) sums k in [q*128, q*128+128)
  {
    const int o = tid & 63, q = tid >> 6;
    const bf16* wrow = WTp + (size_t)(n0 + o) * 512 + q * 128;
    const float* av = abvs + q * 128;
    float acc = 0.f;
#pragma unroll
    for (int kk = 0; kk < 16; ++kk) {
      bf16x8 v = *(const bf16x8*)(wrow + kk * 8);
#pragma unroll
      for (int j = 0; j < 8; ++j) acc += (float)v[j] * av[kk * 8 + j];
    }
    dvp[o][q] = acc;
  }
  // visibility covered by gemm's internal __syncthreads

  f32x4 acc[4][2];
#pragma unroll
  for (int i = 0; i < 4; ++i)
#pragma unroll
    for (int j = 0; j < 2; ++j) acc[i][j] = (f32x4){0.f, 0.f, 0.f, 0.f};
  gemm128x64_core(Hn + ((size_t)(b * 4096 + m0)) * 512, 512,
                  CT + (size_t)b * 262144 + (size_t)n0 * 512, 512, 8, As, Bs, acc);

  const int lane = tid & 63, w = tid >> 6;
  const int wr = (w >> 1) * 64, wc = (w & 1) * 32;
  const int rr = (lane >> 4) * 4, cc = lane & 15;
#pragma unroll
  for (int i = 0; i < 4; ++i) {
#pragma unroll
    for (int j = 0; j < 2; ++j) {
      const int gm = m0 + wr + i * 16 + rr;
      const int gn = n0 + wc + j * 16 + cc;
      const int c = gn - n0;
      const float add = dvp[c][0] + dvp[c][1] + dvp[c][2] + dvp[c][3] + bp[gn];
#pragma unroll
      for (int jj = 0; jj < 4; ++jj) {
        const size_t off = ((size_t)(b * 4096 + gm + jj)) * 512 + gn;
        out[off] = acc[i][j][jj] + add + x[off];
      }
    }
  }
}

extern "C" void kernel_launch(void* const* d_in, const int* in_sizes, int n_in,
                              void* d_out, int out_size, void* d_ws, size_t ws_size,
                              hipStream_t stream) {
  const float* x   = (const float*)d_in[0];
  const float* wq  = (const float*)d_in[1];
  const float* bq  = (const float*)d_in[2];
  const float* wk  = (const float*)d_in[3];
  const float* bk  = (const float*)d_in[4];
  const float* wv  = (const float*)d_in[5];
  const float* bv  = (const float*)d_in[6];
  const float* wp  = (const float*)d_in[7];
  const float* bp  = (const float*)d_in[8];
  const float* gns = (const float*)d_in[9];
  const float* gnb = (const float*)d_in[10];
  float* out = (float*)d_out;

  const size_t MB = 1ull << 20;
  const size_t KB = 1024;
  char* wsb = (char*)d_ws;
  bf16*   WT     = (bf16*)(wsb);                       // 2 MB
  bf16*   wvb    = (bf16*)(wsb + 2 * MB);              // 512 KB
  float2* stats  = (float2*)(wsb + 2 * MB + 512 * KB);
  float*  s      = (float*)(wsb + 2 * MB + 576 * KB);
  float*  uq     = (float*)(wsb + 2 * MB + 640 * KB);
  float*  vkv    = (float*)(wsb + 2 * MB + 704 * KB);
  float*  attnbv = (float*)(wsb + 2 * MB + 832 * KB);  // 16 KB
  bf16*   Hn     = (bf16*)(wsb + 3 * MB);              // 32 MB
  bf16*   HnT    = (bf16*)(wsb + 35 * MB);             // 32 MB
  bf16*   part   = (bf16*)(wsb + 67 * MB);             // 16 MB [4][8][512][512] bf16
  bf16*   attnT  = (bf16*)(wsb + 67 * MB);             // overlay (part dead after gsumv)
  bf16*   T      = (bf16*)(wsb + 71 * MB);
  bf16*   CT     = (bf16*)(wsb + 75 * MB);
  bf16*   G      = (bf16*)(wsb + 99 * MB);             // 4 MB
  bf16*   M1     = (bf16*)(wsb + 103 * MB);            // 4 MB
  float*  L      = (float*)(wsb + 107 * MB);           // 8 MB

  const long S2 = 512 * 512;

  k_prep      <<<dim3(1280),    dim3(256), 0, stream>>>(x, wq, wk, wv, wp, WT, wvb, s, stats);
  k_gnapply_t <<<dim3(512),     dim3(256), 0, stream>>>(x, stats, gns, gnb, Hn, HnT, s);
  k_gram      <<<dim3(320),     dim3(256), 0, stream>>>(HnT, part);
  k_gsumv     <<<dim3(2064),    dim3(256), 0, stream>>>(part, G, WT, s, uq, vkv);
  k_sg64_bf   <<<dim3(8, 8, 8), dim3(256), 0, stream>>>(WT, 0, G, S2, M1);
  k_sg64_f32  <<<dim3(8, 8, 8), dim3(256), 0, stream>>>(M1, S2, WT + (size_t)512 * 512, 0, L);
  k_smax      <<<dim3(1024),    dim3(256), 0, stream>>>(L, uq, vkv, bq, bk, bv, attnT, attnbv);
  k_sg64_bf   <<<dim3(8, 8, 8), dim3(256), 0, stream>>>(WT + (size_t)3 * 512 * 512, 0, attnT, S2, T);
  k_sg64_bf   <<<dim3(8, 8, 8), dim3(256), 0, stream>>>(T, S2, wvb, 0, CT);
  k_final     <<<dim3(2048),    dim3(256), 0, stream>>>(Hn, CT, attnbv, WT + (size_t)3 * 512 * 512,
                                                        bp, x, out);
}

// Round 12
// 163.628 us; speedup vs baseline: 1.1126x; 1.1126x over previous
//
#include <hip/hip_runtime.h>
#include <hip/hip_bf16.h>

// SelfAttention (channel attention) on MI355X. Inputs fp32, OUTPUT fp32.
//   Hn = GN(x) (bf16, row-major + transposed HnT)
//   G_b = Hn_b^T Hn_b ; L_b = Wq^T G_b Wk + rank-1 bias terms
//   attn_b = softmax_rows(L_b) ; attnbv[k] = attn_b[k,:]·bv
//   CT_b = (Wp^T attn_b) Wv^T ; dv = Wp^T attnbv
//   out = x + Hn CT_b^T + dv + bp
// R12: k_final is a PURE gemm+epilogue again (R6 evidence: every in-kernel
//      dv/abvs prologue variant cost ~15us across R8-R11). dv precomputed by
//      64 extra blocks riding the T-gemm launch (grid z==8 slice).

using bf16   = __bf16;
using bf16x8 = __attribute__((ext_vector_type(8))) __bf16;
using bf16x4 = __attribute__((ext_vector_type(4))) __bf16;
using f32x4  = __attribute__((ext_vector_type(4))) float;

#define DI __device__ __forceinline__

DI void gload16(const bf16* g, bf16* l) {
  __builtin_amdgcn_global_load_lds(
      (const __attribute__((address_space(1))) void*)g,
      (__attribute__((address_space(3))) void*)l, 16, 0, 0);
}

// ---------------- 128x128 tile core: gload_lds staging + XOR-swizzled reads ----
DI void gemm128_core(const bf16* __restrict__ A, long lda,
                     const bf16* __restrict__ B, long ldb,
                     int ksteps, bf16* As, bf16* Bs, f32x4 acc[4][4]) {
  const int tid  = threadIdx.x;
  const int lane = tid & 63;
  const int w    = tid >> 6;
  const int lr   = lane & 15;
  const int lk   = (lane >> 4) * 8;
  const int wr   = (w >> 1) * 64;
  const int wc   = (w & 1) * 64;
  const int sw   = (lr & 7) << 3;

  const int  srow = lane >> 3;                       // 0..7
  const int  ssw  = ((lane & 7) ^ srow) << 3;        // pre-swizzled col
  const bf16* ga = A + (long)(w * 8 + srow) * lda + ssw;
  const bf16* gb = B + (long)(w * 8 + srow) * ldb + ssw;
  bf16* lA = As + w * 512;                           // wave-uniform LDS base
  bf16* lB = Bs + w * 512;

  for (int kt = 0; kt < ksteps; ++kt) {
#pragma unroll
    for (int c = 0; c < 4; ++c) {
      gload16(ga + (long)c * 32 * lda, lA + c * 2048);
      gload16(gb + (long)c * 32 * ldb, lB + c * 2048);
    }
    ga += 64; gb += 64;
    __syncthreads();
#pragma unroll
    for (int kk = 0; kk < 2; ++kk) {
      bf16x8 af[4], bfr[4];
#pragma unroll
      for (int i = 0; i < 4; ++i)
        af[i] = *(const bf16x8*)(As + (wr + i * 16 + lr) * 64 + ((kk * 32 + lk) ^ sw));
#pragma unroll
      for (int i = 0; i < 4; ++i)
        bfr[i] = *(const bf16x8*)(Bs + (wc + i * 16 + lr) * 64 + ((kk * 32 + lk) ^ sw));
#pragma unroll
      for (int i = 0; i < 4; ++i)
#pragma unroll
        for (int j = 0; j < 4; ++j)
          acc[i][j] = __builtin_amdgcn_mfma_f32_16x16x32_bf16(af[i], bfr[j], acc[i][j], 0, 0, 0);
    }
    __syncthreads();
  }
}

// ---------------- 128x64 tile core (k_final) ----------
DI void gemm128x64_core(const bf16* __restrict__ A, long lda,
                        const bf16* __restrict__ B, long ldb,
                        int ksteps, bf16* As, bf16* Bs, f32x4 acc[4][2]) {
  const int tid  = threadIdx.x;
  const int lane = tid & 63;
  const int w    = tid >> 6;
  const int lr   = lane & 15;
  const int lk   = (lane >> 4) * 8;
  const int wr   = (w >> 1) * 64;      // M-half
  const int wc   = (w & 1) * 32;       // N-half
  const int sw   = (lr & 7) << 3;

  const int  srow = lane >> 3;
  const int  ssw  = ((lane & 7) ^ srow) << 3;
  const bf16* ga = A + (long)(w * 8 + srow) * lda + ssw;
  const bf16* gb = B + (long)(w * 8 + srow) * ldb + ssw;
  bf16* lA = As + w * 512;
  bf16* lB = Bs + w * 512;

  for (int kt = 0; kt < ksteps; ++kt) {
#pragma unroll
    for (int c = 0; c < 4; ++c)
      gload16(ga + (long)c * 32 * lda, lA + c * 2048);
#pragma unroll
    for (int c = 0; c < 2; ++c)
      gload16(gb + (long)c * 32 * ldb, lB + c * 2048);
    ga += 64; gb += 64;
    __syncthreads();
#pragma unroll
    for (int kk = 0; kk < 2; ++kk) {
      bf16x8 af[4], bfr[2];
#pragma unroll
      for (int i = 0; i < 4; ++i)
        af[i] = *(const bf16x8*)(As + (wr + i * 16 + lr) * 64 + ((kk * 32 + lk) ^ sw));
#pragma unroll
      for (int j = 0; j < 2; ++j)
        bfr[j] = *(const bf16x8*)(Bs + (wc + j * 16 + lr) * 64 + ((kk * 32 + lk) ^ sw));
#pragma unroll
      for (int i = 0; i < 4; ++i)
#pragma unroll
        for (int j = 0; j < 2; ++j)
          acc[i][j] = __builtin_amdgcn_mfma_f32_16x16x32_bf16(af[i], bfr[j], acc[i][j], 0, 0, 0);
    }
    __syncthreads();
  }
}

// ---------------- 64x64 tile core ----------------
DI void gemm64_core(const bf16* __restrict__ A, long lda,
                    const bf16* __restrict__ B, long ldb,
                    int ksteps, bf16* As, bf16* Bs, f32x4 acc[2][2]) {
  const int tid  = threadIdx.x;
  const int lane = tid & 63;
  const int w    = tid >> 6;
  const int lr   = lane & 15;
  const int lk   = (lane >> 4) * 8;
  const int wr   = (w >> 1) * 32;
  const int wc   = (w & 1) * 32;
  const int sw   = (lr & 7) << 3;

  const int  srow = lane >> 3;
  const int  ssw  = ((lane & 7) ^ srow) << 3;
  const bf16* ga = A + (long)(w * 8 + srow) * lda + ssw;
  const bf16* gb = B + (long)(w * 8 + srow) * ldb + ssw;
  bf16* lA = As + w * 512;
  bf16* lB = Bs + w * 512;

  for (int kt = 0; kt < ksteps; ++kt) {
#pragma unroll
    for (int c = 0; c < 2; ++c) {
      gload16(ga + (long)c * 32 * lda, lA + c * 2048);
      gload16(gb + (long)c * 32 * ldb, lB + c * 2048);
    }
    ga += 64; gb += 64;
    __syncthreads();
#pragma unroll
    for (int kk = 0; kk < 2; ++kk) {
      bf16x8 af[2], bfr[2];
#pragma unroll
      for (int i = 0; i < 2; ++i)
        af[i] = *(const bf16x8*)(As + (wr + i * 16 + lr) * 64 + ((kk * 32 + lk) ^ sw));
#pragma unroll
      for (int i = 0; i < 2; ++i)
        bfr[i] = *(const bf16x8*)(Bs + (wc + i * 16 + lr) * 64 + ((kk * 32 + lk) ^ sw));
#pragma unroll
      for (int i = 0; i < 2; ++i)
#pragma unroll
        for (int j = 0; j < 2; ++j)
          acc[i][j] = __builtin_amdgcn_mfma_f32_16x16x32_bf16(af[i], bfr[j], acc[i][j], 0, 0, 0);
    }
    __syncthreads();
  }
}

// ---------------- prep: GN stats (blocks 0..255) + weight transpose (256..1279) ----------------
__global__ __launch_bounds__(256) void k_prep(const float* __restrict__ x,
                                              const float* __restrict__ wq,
                                              const float* __restrict__ wk,
                                              const float* __restrict__ wv,
                                              const float* __restrict__ wp,
                                              bf16* __restrict__ WT,
                                              bf16* __restrict__ wvb,
                                              float* __restrict__ s,
                                              float2* __restrict__ stats) {
  __shared__ float shm[1056];
  const int tid = threadIdx.x;
  const int bx = blockIdx.x;
  if (bx < 256) {
    const int b = bx >> 5, g = bx & 31;
    const float* base = x + (size_t)b * 4096 * 512 + g * 16;
    float sm = 0.f, ss = 0.f;
    for (int it = 0; it < 64; ++it) {
      const int idx = it * 256 + tid;
      const int p = idx >> 2, c4 = (idx & 3) * 4;
      float4 v = *(const float4*)(base + (size_t)p * 512 + c4);
      sm += v.x + v.y + v.z + v.w;
      ss += v.x * v.x + v.y * v.y + v.z * v.z + v.w * v.w;
    }
    float* rs = shm; float* rss = shm + 256;
    rs[tid] = sm; rss[tid] = ss; __syncthreads();
    for (int off = 128; off; off >>= 1) {
      if (tid < off) { rs[tid] += rs[tid + off]; rss[tid] += rss[tid + off]; }
      __syncthreads();
    }
    if (tid == 0) {
      float mean = rs[0] * (1.f / 65536.f);
      float var  = rss[0] * (1.f / 65536.f) - mean * mean;
      stats[bx] = float2{mean, rsqrtf(var + 1e-5f)};
    }
  } else {
    const int r = bx - 256;             // 0..1023
    const int z = r >> 8;
    const int r2 = r & 255;
    const int bxx = r2 & 15, byy = r2 >> 4;
    const int tx = tid & 31, ty = tid >> 5;
    const float* src = (z == 0) ? wq : (z == 1) ? wk : (z == 2) ? wv : wp;
    const int n0 = bxx * 32, k0 = byy * 32;
    if (z == 0 && byy == 0) s[bxx * 256 + tid] = 0.f;
#pragma unroll
    for (int j = 0; j < 4; ++j) {
      const float v = src[(size_t)(k0 + ty + j * 8) * 512 + n0 + tx];
      shm[(ty + j * 8) * 33 + tx] = v;
      if (z == 2) wvb[(size_t)(k0 + ty + j * 8) * 512 + n0 + tx] = (bf16)v;
    }
    __syncthreads();
#pragma unroll
    for (int j = 0; j < 4; ++j)
      WT[(size_t)(z * 512 + n0 + ty + j * 8) * 512 + k0 + tx] = (bf16)shm[tx * 33 + ty + j * 8];
  }
}

// ---------------- GN apply -> Hn + HnT + col-sums s ----------------
__global__ __launch_bounds__(256) void k_gnapply_t(const float* __restrict__ x,
                                                   const float2* __restrict__ stats,
                                                   const float* __restrict__ gns,
                                                   const float* __restrict__ gnb,
                                                   bf16* __restrict__ Hn,
                                                   bf16* __restrict__ HnT,
                                                   float* __restrict__ s) {
  __shared__ bf16 tile[64 * 516];
  __shared__ float cs[512];
  const int tid = threadIdx.x;
  const int blk = blockIdx.x;       // 0..511
  const int b = blk >> 6, p0 = (blk & 63) * 64;
  cs[tid] = 0.f; cs[tid + 256] = 0.f;
  __syncthreads();

  const int c4 = (tid & 127) * 4;
  const int hi = tid >> 7;
  const float2 st = stats[b * 32 + (c4 >> 4)];
  const float4 sc = *(const float4*)(gns + c4);
  const float4 bi = *(const float4*)(gnb + c4);
  float a0 = 0.f, a1 = 0.f, a2 = 0.f, a3 = 0.f;
  for (int i = 0; i < 32; ++i) {
    const int px = i * 2 + hi;
    const float4 xv = *(const float4*)(x + ((size_t)(b * 4096 + p0 + px)) * 512 + c4);
    const float h0 = (xv.x - st.x) * st.y * sc.x + bi.x;
    const float h1 = (xv.y - st.x) * st.y * sc.y + bi.y;
    const float h2 = (xv.z - st.x) * st.y * sc.z + bi.z;
    const float h3 = (xv.w - st.x) * st.y * sc.w + bi.w;
    a0 += h0; a1 += h1; a2 += h2; a3 += h3;
    bf16x4 hv;
    hv[0] = (bf16)h0; hv[1] = (bf16)h1; hv[2] = (bf16)h2; hv[3] = (bf16)h3;
    *(bf16x4*)(Hn + ((size_t)(b * 4096 + p0 + px)) * 512 + c4) = hv;
    *(bf16x4*)(tile + px * 516 + c4) = hv;
  }
  atomicAdd(&cs[c4 + 0], a0); atomicAdd(&cs[c4 + 1], a1);
  atomicAdd(&cs[c4 + 2], a2); atomicAdd(&cs[c4 + 3], a3);
  __syncthreads();
  atomicAdd(s + b * 512 + tid, cs[tid]);
  atomicAdd(s + b * 512 + 256 + tid, cs[tid + 256]);

  for (int cg = 0; cg < 16; ++cg) {
    const int c  = cg * 32 + (tid >> 3);
    const int so = (tid & 7) * 8;
    bf16x8 pk;
#pragma unroll
    for (int k = 0; k < 8; ++k) pk[k] = tile[(so + k) * 516 + c];
    *(bf16x8*)(HnT + ((size_t)(b * 512 + c)) * 4096 + p0 + so) = pk;
  }
}

// ---------------- Gram: symmetric tiles, split-K=4, xcd==batch; bf16 partials ----------------
__global__ __launch_bounds__(256) void k_gram(const bf16* __restrict__ HnT,
                                              bf16* __restrict__ part) {
  __shared__ bf16 As[128 * 64], Bs[128 * 64];
  const int Lb = blockIdx.x;           // 0..319 ; xcd = Lb%8 = batch
  const int b  = Lb & 7;
  const int idx = Lb >> 3;             // 0..39
  const int sp = idx & 3;
  const int t  = idx >> 2;             // 0..9 upper-tri tile id
  const int m0 = (int)((0x3221110000ull >> (4 * t)) & 15) * 128;
  const int n0 = (int)((0x3323213210ull >> (4 * t)) & 15) * 128;
  f32x4 acc[4][4];
#pragma unroll
  for (int i = 0; i < 4; ++i)
#pragma unroll
    for (int j = 0; j < 4; ++j) acc[i][j] = (f32x4){0.f, 0.f, 0.f, 0.f};
  const bf16* A = HnT + ((size_t)b * 512 + m0) * 4096 + sp * 1024;
  const bf16* B = HnT + ((size_t)b * 512 + n0) * 4096 + sp * 1024;
  gemm128_core(A, 4096, B, 4096, 16, As, Bs, acc);

  const int lane = threadIdx.x & 63, w = threadIdx.x >> 6;
  const int wr = (w >> 1) * 64, wc = (w & 1) * 64;
  const int rr = (lane >> 4) * 4, cc = lane & 15;
  bf16* dst = part + (size_t)(sp * 8 + b) * 262144;
#pragma unroll
  for (int i = 0; i < 4; ++i) {
#pragma unroll
    for (int j = 0; j < 4; ++j) {
      const int gm = m0 + wr + i * 16 + rr;
      const int gn = n0 + wc + j * 16 + cc;
      bf16* p = dst + (size_t)gm * 512 + gn;
      p[0]    = (bf16)acc[i][j][0];
      p[512]  = (bf16)acc[i][j][1];
      p[1024] = (bf16)acc[i][j][2];
      p[1536] = (bf16)acc[i][j][3];
      if (m0 != n0) {                  // mirror (G symmetric)
        bf16x4 pk;
        pk[0] = (bf16)acc[i][j][0]; pk[1] = (bf16)acc[i][j][1];
        pk[2] = (bf16)acc[i][j][2]; pk[3] = (bf16)acc[i][j][3];
        *(bf16x4*)(dst + (size_t)gn * 512 + gm) = pk;
      }
    }
  }
}

// ---------------- gsum (blocks 0..2047) + uq/vkv small gemv (2048..2063) ----------------
__global__ __launch_bounds__(256) void k_gsumv(const bf16* __restrict__ part,
                                               bf16* __restrict__ G,
                                               const bf16* __restrict__ WT,
                                               const float* __restrict__ s,
                                               float* __restrict__ uq,
                                               float* __restrict__ vkv) {
  const int bx = blockIdx.x, tid = threadIdx.x;
  if (bx < 2048) {
    const size_t S8 = (size_t)8 * 262144;
    const size_t i4 = ((size_t)bx * 256 + tid) * 4;
    const bf16x4 a = *(const bf16x4*)(part + i4);
    const bf16x4 c = *(const bf16x4*)(part + i4 + S8);
    const bf16x4 d = *(const bf16x4*)(part + i4 + 2 * S8);
    const bf16x4 e = *(const bf16x4*)(part + i4 + 3 * S8);
    bf16x4 o;
#pragma unroll
    for (int j = 0; j < 4; ++j)
      o[j] = (bf16)((float)a[j] + (float)c[j] + (float)d[j] + (float)e[j]);
    *(bf16x4*)(G + i4) = o;
  } else {
    const int z = bx - 2048;            // 0..15
    const int which = z >> 3, b = z & 7;
    const float* sv = s + b * 512;
    for (int o = tid; o < 512; o += 256) {
      const bf16* row = WT + ((size_t)(which * 512 + o)) * 512;
      float acc = 0.f;
      for (int c = 0; c < 512; c += 8) {
        bf16x8 v = *(const bf16x8*)(row + c);
        const float4 s0 = *(const float4*)(sv + c);
        const float4 s1 = *(const float4*)(sv + c + 4);
        acc += (float)v[0] * s0.x + (float)v[1] * s0.y + (float)v[2] * s0.z +
               (float)v[3] * s0.w + (float)v[4] * s1.x + (float)v[5] * s1.y +
               (float)v[6] * s1.z + (float)v[7] * s1.w;
      }
      (which == 0 ? uq : vkv)[b * 512 + o] = acc;
    }
  }
}

// ---------------- batched small GEMM 512x512x512, bf16 out ----------------
__global__ __launch_bounds__(256) void k_sg64_bf(const bf16* __restrict__ Ab, long a_bs,
                                                 const bf16* __restrict__ Bb, long b_bs,
                                                 bf16* __restrict__ Cb) {
  __shared__ bf16 As[64 * 64], Bs[64 * 64];
  const int b = blockIdx.z;
  const int m0 = blockIdx.y * 64, n0 = blockIdx.x * 64;
  f32x4 acc[2][2];
#pragma unroll
  for (int i = 0; i < 2; ++i)
#pragma unroll
    for (int j = 0; j < 2; ++j) acc[i][j] = (f32x4){0.f, 0.f, 0.f, 0.f};
  gemm64_core(Ab + (size_t)b * a_bs + (size_t)m0 * 512, 512,
              Bb + (size_t)b * b_bs + (size_t)n0 * 512, 512, 8, As, Bs, acc);

  const int lane = threadIdx.x & 63, w = threadIdx.x >> 6;
  const int wr = (w >> 1) * 32, wc = (w & 1) * 32;
  const int rr = (lane >> 4) * 4, cc = lane & 15;
  bf16* dst = Cb + (size_t)b * 262144;
#pragma unroll
  for (int i = 0; i < 2; ++i) {
#pragma unroll
    for (int j = 0; j < 2; ++j) {
      const int gm = m0 + wr + i * 16 + rr;
      const int gn = n0 + wc + j * 16 + cc;
      bf16* p = dst + (size_t)gm * 512 + gn;
      p[0]    = (bf16)acc[i][j][0];
      p[512]  = (bf16)acc[i][j][1];
      p[1024] = (bf16)acc[i][j][2];
      p[1536] = (bf16)acc[i][j][3];
    }
  }
}

// ---------------- T = Wp^T attn (z=0..7) + dv = Wp^T attnbv (z==8 slice) ----------------
__global__ __launch_bounds__(256) void k_sgT(const bf16* __restrict__ WTp,
                                             const bf16* __restrict__ attnT,
                                             bf16* __restrict__ T,
                                             const float* __restrict__ attnbv,
                                             float* __restrict__ dv) {
  const int tid = threadIdx.x;
  if (blockIdx.z == 8) {
    // dv block: batch = blockIdx.y, n-chunk = blockIdx.x (64 cols)
    __shared__ float abvs[512];
    __shared__ float dvp[64][4];
    const int b = blockIdx.y, n0 = blockIdx.x * 64;
    for (int c = tid; c < 512; c += 256) abvs[c] = attnbv[b * 512 + c];
    __syncthreads();
    const int o = tid & 63, q = tid >> 6;
    const bf16* wrow = WTp + (size_t)(n0 + o) * 512 + q * 128;
    float acc = 0.f;
#pragma unroll
    for (int kk = 0; kk < 16; ++kk) {
      bf16x8 v = *(const bf16x8*)(wrow + kk * 8);
#pragma unroll
      for (int j = 0; j < 8; ++j) acc += (float)v[j] * abvs[q * 128 + kk * 8 + j];
    }
    dvp[o][q] = acc;
    __syncthreads();
    if (tid < 64)
      dv[b * 512 + n0 + tid] = dvp[tid][0] + dvp[tid][1] + dvp[tid][2] + dvp[tid][3];
    return;
  }
  __shared__ bf16 As[64 * 64], Bs[64 * 64];
  const int b = blockIdx.z;
  const int m0 = blockIdx.y * 64, n0 = blockIdx.x * 64;
  f32x4 acc[2][2];
#pragma unroll
  for (int i = 0; i < 2; ++i)
#pragma unroll
    for (int j = 0; j < 2; ++j) acc[i][j] = (f32x4){0.f, 0.f, 0.f, 0.f};
  gemm64_core(WTp + (size_t)m0 * 512,
              512, attnT + (size_t)b * 262144 + (size_t)n0 * 512, 512, 8, As, Bs, acc);

  const int lane = tid & 63, w = tid >> 6;
  const int wr = (w >> 1) * 32, wc = (w & 1) * 32;
  const int rr = (lane >> 4) * 4, cc = lane & 15;
  bf16* dst = T + (size_t)b * 262144;
#pragma unroll
  for (int i = 0; i < 2; ++i) {
#pragma unroll
    for (int j = 0; j < 2; ++j) {
      const int gm = m0 + wr + i * 16 + rr;
      const int gn = n0 + wc + j * 16 + cc;
      bf16* p = dst + (size_t)gm * 512 + gn;
      p[0]    = (bf16)acc[i][j][0];
      p[512]  = (bf16)acc[i][j][1];
      p[1024] = (bf16)acc[i][j][2];
      p[1536] = (bf16)acc[i][j][3];
    }
  }
}

// ---------------- batched small GEMM 512x512x512, fp32 out ----------------
__global__ __launch_bounds__(256) void k_sg64_f32(const bf16* __restrict__ Ab, long a_bs,
                                                  const bf16* __restrict__ Bb, long b_bs,
                                                  float* __restrict__ Cb) {
  __shared__ bf16 As[64 * 64], Bs[64 * 64];
  const int b = blockIdx.z;
  const int m0 = blockIdx.y * 64, n0 = blockIdx.x * 64;
  f32x4 acc[2][2];
#pragma unroll
  for (int i = 0; i < 2; ++i)
#pragma unroll
    for (int j = 0; j < 2; ++j) acc[i][j] = (f32x4){0.f, 0.f, 0.f, 0.f};
  gemm64_core(Ab + (size_t)b * a_bs + (size_t)m0 * 512, 512,
              Bb + (size_t)b * b_bs + (size_t)n0 * 512, 512, 8, As, Bs, acc);

  const int lane = threadIdx.x & 63, w = threadIdx.x >> 6;
  const int wr = (w >> 1) * 32, wc = (w & 1) * 32;
  const int rr = (lane >> 4) * 4, cc = lane & 15;
  float* dst = Cb + (size_t)b * 262144;
#pragma unroll
  for (int i = 0; i < 2; ++i) {
#pragma unroll
    for (int j = 0; j < 2; ++j) {
      const int gm = m0 + wr + i * 16 + rr;
      const int gn = n0 + wc + j * 16 + cc;
      float* p = dst + (size_t)gm * 512 + gn;
      p[0]    = acc[i][j][0];
      p[512]  = acc[i][j][1];
      p[1024] = acc[i][j][2];
      p[1536] = acc[i][j][3];
    }
  }
}

// ---------------- softmax (4 rows/block, wave-shuffle) -> attnT + attnbv ----------------
__global__ __launch_bounds__(256) void k_smax(const float* __restrict__ L,
                                              const float* __restrict__ uq,
                                              const float* __restrict__ vkv,
                                              const float* __restrict__ bq,
                                              const float* __restrict__ bk,
                                              const float* __restrict__ bv,
                                              bf16* __restrict__ attnT,
                                              float* __restrict__ attnbv) {
  __shared__ bf16 p[4][512];
  const int tid = threadIdx.x;
  const int w = tid >> 6, l = tid & 63;
  const int blk = blockIdx.x;          // 0..1023, 4 rows each
  const int gr = blk * 4 + w;          // global row
  const int b = gr >> 9, i = gr & 511;
  const int c = l * 8;

  const float r  = uq[b * 512 + i];
  const float q0 = bq[i];
  const float* lp = L + (size_t)gr * 512 + c;
  const float4 l0 = *(const float4*)lp;
  const float4 l1 = *(const float4*)(lp + 4);
  const float4 k0 = *(const float4*)(bk + c);
  const float4 k1 = *(const float4*)(bk + c + 4);
  const float4 g0 = *(const float4*)(vkv + b * 512 + c);
  const float4 g1 = *(const float4*)(vkv + b * 512 + c + 4);
  float v[8];
  v[0] = l0.x + r * k0.x + q0 * (g0.x + 4096.f * k0.x);
  v[1] = l0.y + r * k0.y + q0 * (g0.y + 4096.f * k0.y);
  v[2] = l0.z + r * k0.z + q0 * (g0.z + 4096.f * k0.z);
  v[3] = l0.w + r * k0.w + q0 * (g0.w + 4096.f * k0.w);
  v[4] = l1.x + r * k1.x + q0 * (g1.x + 4096.f * k1.x);
  v[5] = l1.y + r * k1.y + q0 * (g1.y + 4096.f * k1.y);
  v[6] = l1.z + r * k1.z + q0 * (g1.z + 4096.f * k1.z);
  v[7] = l1.w + r * k1.w + q0 * (g1.w + 4096.f * k1.w);

  float mx = v[0];
#pragma unroll
  for (int j = 1; j < 8; ++j) mx = fmaxf(mx, v[j]);
  for (int off = 32; off; off >>= 1) mx = fmaxf(mx, __shfl_xor(mx, off));
  float e[8], sm = 0.f;
#pragma unroll
  for (int j = 0; j < 8; ++j) { e[j] = __expf(v[j] - mx); sm += e[j]; }
  for (int off = 32; off; off >>= 1) sm += __shfl_xor(sm, off);
  const float inv = 1.f / sm;

  const float4 b0 = *(const float4*)(bv + c);
  const float4 b1 = *(const float4*)(bv + c + 4);
  float ab = e[0] * b0.x + e[1] * b0.y + e[2] * b0.z + e[3] * b0.w +
             e[4] * b1.x + e[5] * b1.y + e[6] * b1.z + e[7] * b1.w;
  ab *= inv;
  for (int off = 32; off; off >>= 1) ab += __shfl_xor(ab, off);
  if (l == 0) attnbv[gr] = ab;

  bf16x8 o;
#pragma unroll
  for (int j = 0; j < 8; ++j) o[j] = (bf16)(e[j] * inv);
  *(bf16x8*)(&p[w][c]) = o;
  __syncthreads();

  const int i0 = (blk * 4) & 511;
  for (int n = tid; n < 512; n += 256) {
    bf16x4 t;
    t[0] = p[0][n]; t[1] = p[1][n]; t[2] = p[2][n]; t[3] = p[3][n];
    *(bf16x4*)(attnT + (size_t)b * 262144 + (size_t)n * 512 + i0) = t;
  }
}

// ---------------- final: out = x + Hn CT^T + dv + bp ; pure gemm+epilogue ----------------
__global__ __launch_bounds__(256) void k_final(const bf16* __restrict__ Hn,
                                               const bf16* __restrict__ CT,
                                               const float* __restrict__ dv,
                                               const float* __restrict__ bp,
                                               const float* __restrict__ x,
                                               float* __restrict__ out) {
  __shared__ bf16 As[128 * 64], Bs[64 * 64];
  const int Lb = blockIdx.x;           // 0..2047 ; xcd = Lb%8 = batch
  const int b  = Lb & 7;
  const int idx = Lb >> 3;             // 0..255
  const int m0 = (idx >> 3) * 128;     // 32 M-tiles
  const int n0 = (idx & 7) * 64;       // 8 N-tiles
  const int tid = threadIdx.x;

  f32x4 acc[4][2];
#pragma unroll
  for (int i = 0; i < 4; ++i)
#pragma unroll
    for (int j = 0; j < 2; ++j) acc[i][j] = (f32x4){0.f, 0.f, 0.f, 0.f};
  gemm128x64_core(Hn + ((size_t)(b * 4096 + m0)) * 512, 512,
                  CT + (size_t)b * 262144 + (size_t)n0 * 512, 512, 8, As, Bs, acc);

  const int lane = tid & 63, w = tid >> 6;
  const int wr = (w >> 1) * 64, wc = (w & 1) * 32;
  const int rr = (lane >> 4) * 4, cc = lane & 15;
#pragma unroll
  for (int i = 0; i < 4; ++i) {
#pragma unroll
    for (int j = 0; j < 2; ++j) {
      const int gm = m0 + wr + i * 16 + rr;
      const int gn = n0 + wc + j * 16 + cc;
      const float add = dv[b * 512 + gn] + bp[gn];
#pragma unroll
      for (int jj = 0; jj < 4; ++jj) {
        const size_t off = ((size_t)(b * 4096 + gm + jj)) * 512 + gn;
        out[off] = acc[i][j][jj] + add + x[off];
      }
    }
  }
}

extern "C" void kernel_launch(void* const* d_in, const int* in_sizes, int n_in,
                              void* d_out, int out_size, void* d_ws, size_t ws_size,
                              hipStream_t stream) {
  const float* x   = (const float*)d_in[0];
  const float* wq  = (const float*)d_in[1];
  const float* bq  = (const float*)d_in[2];
  const float* wk  = (const float*)d_in[3];
  const float* bk  = (const float*)d_in[4];
  const float* wv  = (const float*)d_in[5];
  const float* bv  = (const float*)d_in[6];
  const float* wp  = (const float*)d_in[7];
  const float* bp  = (const float*)d_in[8];
  const float* gns = (const float*)d_in[9];
  const float* gnb = (const float*)d_in[10];
  float* out = (float*)d_out;

  const size_t MB = 1ull << 20;
  const size_t KB = 1024;
  char* wsb = (char*)d_ws;
  bf16*   WT     = (bf16*)(wsb);                       // 2 MB
  bf16*   wvb    = (bf16*)(wsb + 2 * MB);              // 512 KB
  float2* stats  = (float2*)(wsb + 2 * MB + 512 * KB);
  float*  s      = (float*)(wsb + 2 * MB + 576 * KB);
  float*  uq     = (float*)(wsb + 2 * MB + 640 * KB);
  float*  vkv    = (float*)(wsb + 2 * MB + 704 * KB);
  float*  dv     = (float*)(wsb + 2 * MB + 768 * KB);  // 16 KB
  float*  attnbv = (float*)(wsb + 2 * MB + 832 * KB);  // 16 KB
  bf16*   Hn     = (bf16*)(wsb + 3 * MB);              // 32 MB
  bf16*   HnT    = (bf16*)(wsb + 35 * MB);             // 32 MB
  bf16*   part   = (bf16*)(wsb + 67 * MB);             // 16 MB [4][8][512][512] bf16
  bf16*   attnT  = (bf16*)(wsb + 67 * MB);             // overlay (part dead after gsumv)
  bf16*   T      = (bf16*)(wsb + 71 * MB);
  bf16*   CT     = (bf16*)(wsb + 75 * MB);
  bf16*   G      = (bf16*)(wsb + 99 * MB);             // 4 MB
  bf16*   M1     = (bf16*)(wsb + 103 * MB);            // 4 MB
  float*  L      = (float*)(wsb + 107 * MB);           // 8 MB

  const long S2 = 512 * 512;

  k_prep      <<<dim3(1280),    dim3(256), 0, stream>>>(x, wq, wk, wv, wp, WT, wvb, s, stats);
  k_gnapply_t <<<dim3(512),     dim3(256), 0, stream>>>(x, stats, gns, gnb, Hn, HnT, s);
  k_gram      <<<dim3(320),     dim3(256), 0, stream>>>(HnT, part);
  k_gsumv     <<<dim3(2064),    dim3(256), 0, stream>>>(part, G, WT, s, uq, vkv);
  k_sg64_bf   <<<dim3(8, 8, 8), dim3(256), 0, stream>>>(WT, 0, G, S2, M1);
  k_sg64_f32  <<<dim3(8, 8, 8), dim3(256), 0, stream>>>(M1, S2, WT + (size_t)512 * 512, 0, L);
  k_smax      <<<dim3(1024),    dim3(256), 0, stream>>>(L, uq, vkv, bq, bk, bv, attnT, attnbv);
  k_sgT       <<<dim3(8, 8, 9), dim3(256), 0, stream>>>(WT + (size_t)3 * 512 * 512, attnT, T,
                                                        attnbv, dv);
  k_sg64_bf   <<<dim3(8, 8, 8), dim3(256), 0, stream>>>(T, S2, wvb, 0, CT);
  k_final     <<<dim3(2048),    dim3(256), 0, stream>>>(Hn, CT, dv, bp, x, out);
}